// Round 7
// baseline (62021.124 us; speedup 1.0000x reference)
//
#include <hip/hip_runtime.h>

#define BATCH 32
#define SEQ   2048
#define ISZ   512
#define HSZ   512
#define GRID  256
#define TPB   512
#define NB    4      // batches per group (8 groups x 32 blocks)
#define NPROD 32     // producer blocks per group
#define ND    16     // dims per block
#define SPIN_CAP 2000000

typedef unsigned int u32;
typedef unsigned long long u64;

// Sync protocol: round-0's PROVEN beacon induction with round-0's PROVEN
// poll topology (few lanes poll, block waits at barrier):
//   producer wave0: agent h-stores (32x8B, ONE instruction) -> s_waitcnt
//   vmcnt(0) (ack at coherence point) -> ONE monotone beacon word := t+1.
//   consumer wave0 lanes <32: poll beacon[p] >= t (1 lane per producer) ->
//   S0 barrier -> ALL threads read h[t-1] ONCE -> stage LDS.
// Measured lessons encoded:
//   r1/r2/r5: wide data-polling of write-hot lines = LLC storm (190 GB).
//   r6: per-thread beacon polling = fabric storm (143 GB; 8x pollers of
//       r0 gave 500x fetch). Poll lanes MUST be ~1 per producer per block.
// vs round 0 (16.4 ms), pure deletions from the chain:
//   - gpre LDS transpose + serial wave-0 gate math gone (gates replicated
//     per 32-lane group; thread owns 1 dim x 4 gates)
//   - producer tail: h funneled via LDS, wave0 stores 32x8B -> faster ack
//   - fan-in 64 -> 32 producers/group (straggler max halved)
// ws: 256 beacon u32 (zeroed each launch). h exchanged through `out`.

__device__ __forceinline__ float u2f(u32 u){ union{u32 u; float f;}c; c.u=u; return c.f; }
__device__ __forceinline__ u32 f2u(float f){ union{float f; u32 u;}c; c.f=f; return c.u; }

__device__ __forceinline__ u32 ld_agent_u32(const u32* p){
    return __hip_atomic_load(p, __ATOMIC_RELAXED, __HIP_MEMORY_SCOPE_AGENT);
}
__device__ __forceinline__ u64 ld_agent_u64(const u64* p){
    return __hip_atomic_load(p, __ATOMIC_RELAXED, __HIP_MEMORY_SCOPE_AGENT);
}
__device__ __forceinline__ void st_agent_u32(u32* p, u32 v){
    __hip_atomic_store(p, v, __ATOMIC_RELAXED, __HIP_MEMORY_SCOPE_AGENT);
}
__device__ __forceinline__ void st_agent_u64(u64* p, u64 v){
    __hip_atomic_store(p, v, __ATOMIC_RELAXED, __HIP_MEMORY_SCOPE_AGENT);
}

#define FMA16(a, W) \
    a = fmaf(W[0].x,o0.x,a); a = fmaf(W[0].y,o0.y,a); a = fmaf(W[0].z,o0.z,a); a = fmaf(W[0].w,o0.w,a); \
    a = fmaf(W[1].x,o1.x,a); a = fmaf(W[1].y,o1.y,a); a = fmaf(W[1].z,o1.z,a); a = fmaf(W[1].w,o1.w,a); \
    a = fmaf(W[2].x,o2.x,a); a = fmaf(W[2].y,o2.y,a); a = fmaf(W[2].z,o2.z,a); a = fmaf(W[2].w,o2.w,a); \
    a = fmaf(W[3].x,o3.x,a); a = fmaf(W[3].y,o3.y,a); a = fmaf(W[3].z,o3.z,a); a = fmaf(W[3].w,o3.w,a);

#define GATE(b, cprev, huout) { \
    float iv = acc[0*4+(b)] + bias0; \
    float fv = acc[1*4+(b)] + bias1; \
    float gv = acc[2*4+(b)] + bias2; \
    float ov = acc[3*4+(b)] + bias3; \
    iv = 1.f/(1.f+__expf(-iv)); \
    fv = 1.f/(1.f+__expf(-fv)); \
    gv = tanhf(gv); \
    ov = 1.f/(1.f+__expf(-ov)); \
    float c = fv*(cprev) + iv*gv; \
    float h = ov*tanhf(c); \
    (cprev) = c; \
    (huout) = f2u(h); }

__global__ __launch_bounds__(TPB)
void lstm_persistent(const float* __restrict__ inp,
                     const float* __restrict__ w_ii, const float* __restrict__ w_hi,
                     const float* __restrict__ b_ii, const float* __restrict__ b_hi,
                     const float* __restrict__ w_if, const float* __restrict__ w_hf,
                     const float* __restrict__ b_if, const float* __restrict__ b_hf,
                     const float* __restrict__ w_io, const float* __restrict__ w_ho,
                     const float* __restrict__ b_io, const float* __restrict__ b_ho,
                     const float* __restrict__ w_ig, const float* __restrict__ w_hg,
                     const float* __restrict__ b_ig, const float* __restrict__ b_hg,
                     float* __restrict__ out, u32* __restrict__ ws)
{
    __shared__ float lh[2][NB * HSZ];       // double-buffered staged h (16 KB)
    __shared__ u32 hout[64];                // [batch][dim] h funnel for wave 0

    const int tid = threadIdx.x;
    const int g   = blockIdx.x;

    const int grp  = g >> 5;                // 8 groups of 32 blocks
    const int rank = g & 31;
    const int B4 = grp * NB;                // this group's 4 batches
    const int d0 = rank * ND;               // this block's 16 dims
    const int dr = tid >> 5;                // dim-within-block 0..15
    const int ks = tid & 31;                // 16-float K-slice
    const int xr = (ks >> 1) & 7;           // hdot XOR swizzle term
    const int bt = tid >> 7;                // staging batch 0..3
    const int cc = tid & 127;               // staging quad 0..127
    const int lb = tid & 31;                // lane within 32-group

    const float* whp[4] = { w_hi, w_hf, w_hg, w_ho };
    const float* wxp[4] = { w_ii, w_if, w_ig, w_io };
    const float* bip[4] = { b_ii, b_if, b_ig, b_io };
    const float* bhp[4] = { b_hi, b_hf, b_hg, b_ho };

    const float bias0 = bip[0][d0 + dr] + bhp[0][d0 + dr];
    const float bias1 = bip[1][d0 + dr] + bhp[1][d0 + dr];
    const float bias2 = bip[2][d0 + dr] + bhp[2][d0 + dr];
    const float bias3 = bip[3][d0 + dr] + bhp[3][d0 + dr];

    // weights in registers: 4 gate-rows (dim d0+dr) x 16-float K-slice
    float4 wx[4][4], wh[4][4];
    #pragma unroll
    for (int gi = 0; gi < 4; ++gi) {
        const float* xs = wxp[gi] + (size_t)(d0 + dr) * HSZ + ks * 16;
        const float* hs = whp[gi] + (size_t)(d0 + dr) * HSZ + ks * 16;
        #pragma unroll
        for (int j = 0; j < 4; ++j) {
            wx[gi][j] = *(const float4*)(xs + 4 * j);
            wh[gi][j] = *(const float4*)(hs + 4 * j);
        }
    }

    float xpc[16], xpn[16];                 // x-partials [gate*4 + batch]

    auto xproj = [&](int tt, int blo, int bhi, float* q) {
        #pragma unroll
        for (int b = 0; b < 4; ++b) {
            if (b < blo || b >= bhi) continue;
            const float* src = inp + ((size_t)(B4 + b) * SEQ + tt) * ISZ + ks * 16;
            float4 o0 = *(const float4*)(src);
            float4 o1 = *(const float4*)(src + 4);
            float4 o2 = *(const float4*)(src + 8);
            float4 o3 = *(const float4*)(src + 12);
            #pragma unroll
            for (int gi = 0; gi < 4; ++gi) {
                float a = 0.f;
                FMA16(a, wx[gi]);
                q[gi * 4 + b] = a;
            }
        }
    };

    xproj(0, 0, 4, xpc);                    // prologue

    float c0 = 0.f, c1 = 0.f, c2 = 0.f, c3 = 0.f;
    u32 hu0 = 0, hu1 = 0, hu2 = 0, hu3 = 0;

    for (int t = 0; t < SEQ; ++t) {
        const int slr = (t - 1) & 1;
        if (t > 0) {
            // ---- 1: xproj(t+1) first half (hides producer-tail latency) --
            if (t + 1 < SEQ) xproj(t + 1, 0, 2, xpn);

            // ---- 2: beacon poll, ONE lane per producer (32 lanes total) --
            if (tid < NPROD) {
                const u32* bp = ws + grp * NPROD + tid;
                u32 bv = ld_agent_u32(bp);
                int spin = 0;
                while (bv < (u32)t) {
                    __builtin_amdgcn_s_sleep(1);
                    bv = ld_agent_u32(bp);
                    if (++spin > SPIN_CAP) break;
                }
            }
            __syncthreads();                // (S0) all producers' h visible

            // ---- 3: single bulk read of own 16 B of h[t-1] ----
            const u64* src = (const u64*)(out + (size_t)(t - 1) * BATCH * HSZ
                                              + (size_t)(B4 + bt) * HSZ + cc * 4);
            u64 v0 = ld_agent_u64(src);
            u64 v1 = ld_agent_u64(src + 1);

            // ---- 4: xproj(t+1) second half hides the read latency ----
            if (t + 1 < SEQ) xproj(t + 1, 2, 4, xpn);

            // ---- 5: stage into LDS, XOR-swizzled ----
            float4 w;
            w.x = u2f((u32)v0); w.y = u2f((u32)(v0 >> 32));
            w.z = u2f((u32)v1); w.w = u2f((u32)(v1 >> 32));
            const int qs = cc ^ ((cc >> 3) & 7);
            *(float4*)(&lh[slr][bt * 512 + qs * 4]) = w;
        } else {
            xproj(1, 0, 4, xpn);
        }
        __syncthreads();                    // (S) staged

        // ---- 6: h-dot on top of x partials ----
        float acc[16];
        #pragma unroll
        for (int i = 0; i < 16; ++i) acc[i] = xpc[i];
        if (t > 0) {
            #pragma unroll
            for (int b = 0; b < 4; ++b) {
                const float* hb = &lh[slr][b * 512];
                float4 o0 = *(const float4*)(hb + ((4 * ks + 0) ^ xr) * 4);
                float4 o1 = *(const float4*)(hb + ((4 * ks + 1) ^ xr) * 4);
                float4 o2 = *(const float4*)(hb + ((4 * ks + 2) ^ xr) * 4);
                float4 o3 = *(const float4*)(hb + ((4 * ks + 3) ^ xr) * 4);
                #pragma unroll
                for (int gi = 0; gi < 4; ++gi) {
                    float a = acc[gi * 4 + b];
                    FMA16(a, wh[gi]);
                    acc[gi * 4 + b] = a;
                }
            }
        }
        // ---- 7: butterfly reduce (all lanes get full sums) ----
        #pragma unroll
        for (int m = 16; m >= 1; m >>= 1) {
            #pragma unroll
            for (int i = 0; i < 16; ++i) acc[i] += __shfl_xor(acc[i], m);
        }

        // ---- 8: gates replicated; funnel h to LDS ----
        GATE(0, c0, hu0)
        GATE(1, c1, hu1)
        GATE(2, c2, hu2)
        GATE(3, c3, hu3)
        if (lb < 4)
            hout[lb * 16 + dr] = lb == 0 ? hu0 : lb == 1 ? hu1 : lb == 2 ? hu2 : hu3;
        __syncthreads();                    // (B) hout ready; lh free

        // ---- 9: wave0: 32x8B agent h-store -> ack -> beacon ----
        if (tid < 32) {
            const u32 lo = hout[tid * 2], hi = hout[tid * 2 + 1];
            const int b2 = tid >> 3, dp = (tid * 2) & 15;
            st_agent_u64((u64*)(out + (size_t)t * BATCH * HSZ
                                    + (size_t)(B4 + b2) * HSZ + d0 + dp),
                         (u64)lo | ((u64)hi << 32));
            if (t + 1 < SEQ) {
                asm volatile("s_waitcnt vmcnt(0)" ::: "memory");   // ack'd
                if (tid == 0) st_agent_u32(ws + grp * NPROD + rank, (u32)(t + 1));
            }
        }

        #pragma unroll
        for (int i = 0; i < 16; ++i) xpc[i] = xpn[i];
    }

    // epilogue: h_last, c_last
    if (lb < 4) {
        const u32 hu  = lb == 0 ? hu0 : lb == 1 ? hu1 : lb == 2 ? hu2 : hu3;
        const float cv = lb == 0 ? c0 : lb == 1 ? c1 : lb == 2 ? c2 : c3;
        size_t base = (size_t)SEQ * BATCH * HSZ;
        out[base + (size_t)(B4 + lb) * HSZ + (d0 + dr)] = u2f(hu);                       // h_last
        out[base + (size_t)BATCH * HSZ + (size_t)(B4 + lb) * HSZ + (d0 + dr)] = cv;      // c_last
    }
}

extern "C" void kernel_launch(void* const* d_in, const int* in_sizes, int n_in,
                              void* d_out, int out_size, void* d_ws, size_t ws_size,
                              hipStream_t stream) {
    const float* inp  = (const float*)d_in[0];
    const float* w_ii = (const float*)d_in[1];
    const float* w_hi = (const float*)d_in[2];
    const float* b_ii = (const float*)d_in[3];
    const float* b_hi = (const float*)d_in[4];
    const float* w_if = (const float*)d_in[5];
    const float* w_hf = (const float*)d_in[6];
    const float* b_if = (const float*)d_in[7];
    const float* b_hf = (const float*)d_in[8];
    const float* w_io = (const float*)d_in[9];
    const float* w_ho = (const float*)d_in[10];
    const float* b_io = (const float*)d_in[11];
    const float* b_ho = (const float*)d_in[12];
    const float* w_ig = (const float*)d_in[13];
    const float* w_hg = (const float*)d_in[14];
    const float* b_ig = (const float*)d_in[15];
    const float* b_hg = (const float*)d_in[16];
    float* out = (float*)d_out;
    u32* ws = (u32*)d_ws;

    hipMemsetAsync(d_ws, 0, 4096, stream);  // zero beacons each launch

    void* args[] = { (void*)&inp,
                     (void*)&w_ii, (void*)&w_hi, (void*)&b_ii, (void*)&b_hi,
                     (void*)&w_if, (void*)&w_hf, (void*)&b_if, (void*)&b_hf,
                     (void*)&w_io, (void*)&w_ho, (void*)&b_io, (void*)&b_ho,
                     (void*)&w_ig, (void*)&w_hg, (void*)&b_ig, (void*)&b_hg,
                     (void*)&out, (void*)&ws };
    hipError_t err = hipLaunchCooperativeKernel((const void*)lstm_persistent,
                                                dim3(GRID), dim3(TPB), args, 0, stream);
    if (err != hipSuccess) {
        lstm_persistent<<<dim3(GRID), dim3(TPB), 0, stream>>>(
            inp, w_ii, w_hi, b_ii, b_hi, w_if, w_hf, b_if, b_hf,
            w_io, w_ho, b_io, b_ho, w_ig, w_hg, b_ig, b_hg, out, ws);
    }
}

// Round 8
// 58073.102 us; speedup vs baseline: 1.0680x; 1.0680x over previous
//
#include <hip/hip_runtime.h>

#define BATCH 32
#define SEQ   2048
#define ISZ   512
#define HSZ   512
#define GRID  256
#define TPB   1024
#define NB    4      // batches per group (8 groups x 32 blocks)
#define NPROD 32     // producer blocks per group
#define ND    16     // dims per block
#define SPIN_CAP 2000000

typedef unsigned int u32;
typedef unsigned long long u64;

// Round-0's PROVEN beacon skeleton, re-dimensioned to TPB=1024.
//
// SPILL LESSON (r5/r6/r7): 4-gate-per-thread weight layouts need 128 VGPRs
// of weights -> compiler spills to scratch -> 137 GB/launch of scratch reads
// (FETCH_SIZE 143-190 GB, 30-45us steps). No-spill constraint: <=64 weight
// floats/thread (2 rows x 16-float slice x {Wx,Wh}), i.e. threads = rows*16.
// TPB=1024 gives rows=64 = 4 gates x 16 dims -> 32 producers/group,
// 4 batches/group, per-thread FMA halved vs r0. VGPR stays ~r0 (124).
//
// Sync protocol (r0, bit-for-bit): producer wave0 (64 lanes): agent h-stores
// -> s_waitcnt vmcnt(0) (ack at coherence point) -> ONE monotone beacon
// word := t+1. Consumer: 32 lanes poll 32 beacons (1 lane/producer) -> S0
// barrier -> bulk read h[t-1] ONCE -> stage LDS. Poll topology lessons
// (r1/r2/r5: wide data-polls = LLC storm; r6: per-thread beacon polls):
// poll lanes stay at 1 per producer per block.
// ws: 256 beacon u32 (zeroed each launch). h exchanged through `out`.

__device__ __forceinline__ float u2f(u32 u){ union{u32 u; float f;}c; c.u=u; return c.f; }
__device__ __forceinline__ u32 f2u(float f){ union{float f; u32 u;}c; c.f=f; return c.u; }

__device__ __forceinline__ u32 ld_agent_u32(const u32* p){
    return __hip_atomic_load(p, __ATOMIC_RELAXED, __HIP_MEMORY_SCOPE_AGENT);
}
__device__ __forceinline__ u64 ld_agent_u64(const u64* p){
    return __hip_atomic_load(p, __ATOMIC_RELAXED, __HIP_MEMORY_SCOPE_AGENT);
}
__device__ __forceinline__ void st_agent_u32(u32* p, u32 v){
    __hip_atomic_store(p, v, __ATOMIC_RELAXED, __HIP_MEMORY_SCOPE_AGENT);
}
__device__ __forceinline__ void st_agent_f32(float* p, float v){
    __hip_atomic_store(p, v, __ATOMIC_RELAXED, __HIP_MEMORY_SCOPE_AGENT);
}

__global__ __launch_bounds__(TPB)
void lstm_persistent(const float* __restrict__ inp,
                     const float* __restrict__ w_ii, const float* __restrict__ w_hi,
                     const float* __restrict__ b_ii, const float* __restrict__ b_hi,
                     const float* __restrict__ w_if, const float* __restrict__ w_hf,
                     const float* __restrict__ b_if, const float* __restrict__ b_hf,
                     const float* __restrict__ w_io, const float* __restrict__ w_ho,
                     const float* __restrict__ b_io, const float* __restrict__ b_ho,
                     const float* __restrict__ w_ig, const float* __restrict__ w_hg,
                     const float* __restrict__ b_ig, const float* __restrict__ b_hg,
                     float* __restrict__ out, u32* __restrict__ ws)
{
    __shared__ float lh[NB * HSZ];          // staged h[t-1], XOR-swizzled (8 KB)
    __shared__ float gpre[64][5];           // [row][batch(+pad)] preactivations
    __shared__ float lbias[64];

    const int tid = threadIdx.x;
    const int g   = blockIdx.x;

    const int grp  = g >> 5;                // 8 groups of 32 blocks
    const int rank = g & 31;
    const int B4 = grp * NB;                // this group's 4 batches
    const int d0 = rank * ND;               // this block's 16 dims

    const int rp = tid >> 5;                // row pair 0..31 (rows 2rp,2rp+1 of 64)
    const int ks = tid & 31;                // 16-float K-slice
    const int r0 = 2 * rp;                  // row = gate*16 + dim-local
    const int gg = r0 >> 4;                 // gate index 0..3
    const int dl0 = r0 & 15, dl1 = dl0 + 1; // local dims
    const int xr  = (ks >> 1) & 7;          // hdot XOR term
    // staging ids (tid < 512 stage 16 B each)
    const int bt = tid >> 7;                // batch 0..3
    const int cc = tid & 127;               // 4-float quad 0..127

    const float* whp[4] = { w_hi, w_hf, w_hg, w_ho };
    const float* wxp[4] = { w_ii, w_if, w_ig, w_io };
    const float* bip[4] = { b_ii, b_if, b_ig, b_io };
    const float* bhp[4] = { b_hi, b_hf, b_hg, b_ho };

    if (tid < 64) {
        int g2 = tid >> 4, d2 = tid & 15;
        lbias[tid] = bip[g2][d0 + d2] + bhp[g2][d0 + d2];
    }

    // weights in registers: 2 rows x 16-float slice of Wx and Wh = 64 floats
    float4 wx0[4], wx1[4], wh0[4], wh1[4];
    {
        const float* x0 = wxp[gg] + (size_t)(d0 + dl0) * HSZ + ks * 16;
        const float* x1 = wxp[gg] + (size_t)(d0 + dl1) * HSZ + ks * 16;
        const float* h0 = whp[gg] + (size_t)(d0 + dl0) * HSZ + ks * 16;
        const float* h1 = whp[gg] + (size_t)(d0 + dl1) * HSZ + ks * 16;
        #pragma unroll
        for (int j = 0; j < 4; ++j) {
            wx0[j] = *(const float4*)(x0 + 4 * j);
            wx1[j] = *(const float4*)(x1 + 4 * j);
            wh0[j] = *(const float4*)(h0 + 4 * j);
            wh1[j] = *(const float4*)(h1 + 4 * j);
        }
    }
    __syncthreads();

    float xpc0[4], xpc1[4], xpn0[4], xpn1[4];

    auto xproj = [&](int tt, int blo, int bhi, float* q0, float* q1) {
        for (int b = blo; b < bhi; ++b) {
            const float* src = inp + ((size_t)(B4 + b) * SEQ + tt) * ISZ + ks * 16;
            float4 o0 = *(const float4*)(src);
            float4 o1 = *(const float4*)(src + 4);
            float4 o2 = *(const float4*)(src + 8);
            float4 o3 = *(const float4*)(src + 12);
            float a0 = 0.f, a1 = 0.f;
            a0 = fmaf(wx0[0].x,o0.x,a0); a0 = fmaf(wx0[0].y,o0.y,a0); a0 = fmaf(wx0[0].z,o0.z,a0); a0 = fmaf(wx0[0].w,o0.w,a0);
            a0 = fmaf(wx0[1].x,o1.x,a0); a0 = fmaf(wx0[1].y,o1.y,a0); a0 = fmaf(wx0[1].z,o1.z,a0); a0 = fmaf(wx0[1].w,o1.w,a0);
            a0 = fmaf(wx0[2].x,o2.x,a0); a0 = fmaf(wx0[2].y,o2.y,a0); a0 = fmaf(wx0[2].z,o2.z,a0); a0 = fmaf(wx0[2].w,o2.w,a0);
            a0 = fmaf(wx0[3].x,o3.x,a0); a0 = fmaf(wx0[3].y,o3.y,a0); a0 = fmaf(wx0[3].z,o3.z,a0); a0 = fmaf(wx0[3].w,o3.w,a0);
            a1 = fmaf(wx1[0].x,o0.x,a1); a1 = fmaf(wx1[0].y,o0.y,a1); a1 = fmaf(wx1[0].z,o0.z,a1); a1 = fmaf(wx1[0].w,o0.w,a1);
            a1 = fmaf(wx1[1].x,o1.x,a1); a1 = fmaf(wx1[1].y,o1.y,a1); a1 = fmaf(wx1[1].z,o1.z,a1); a1 = fmaf(wx1[1].w,o1.w,a1);
            a1 = fmaf(wx1[2].x,o2.x,a1); a1 = fmaf(wx1[2].y,o2.y,a1); a1 = fmaf(wx1[2].z,o2.z,a1); a1 = fmaf(wx1[2].w,o2.w,a1);
            a1 = fmaf(wx1[3].x,o3.x,a1); a1 = fmaf(wx1[3].y,o3.y,a1); a1 = fmaf(wx1[3].z,o3.z,a1); a1 = fmaf(wx1[3].w,o3.w,a1);
            q0[b] = a0; q1[b] = a1;
        }
    };

    xproj(0, 0, 4, xpc0, xpc1);             // prologue

    float h_keep = 0.f, c_keep = 0.f, c_reg = 0.f;

    for (int t = 0; t < SEQ; ++t) {
        if (t > 0) {
            // ---- 1: xproj(t+1) first half (hides producer-tail latency) --
            if (t + 1 < SEQ) xproj(t + 1, 0, 2, xpn0, xpn1);

            // ---- 2: beacon poll, ONE lane per producer (32 lanes) ----
            if (tid < NPROD) {
                const u32* bp = ws + grp * NPROD + tid;
                u32 bv = ld_agent_u32(bp);
                int spin = 0;
                while (bv < (u32)t) {
                    __builtin_amdgcn_s_sleep(1);
                    bv = ld_agent_u32(bp);
                    if (++spin > SPIN_CAP) break;
                }
            }
            __syncthreads();                // (S0) all producers' h visible

            // ---- 3: bulk read, 16 B per stager (tid < 512) ----
            u64 v0 = 0, v1 = 0;
            if (tid < 512) {
                const u64* src = (const u64*)(out + (size_t)(t - 1) * BATCH * HSZ
                                                  + (size_t)(B4 + bt) * HSZ + cc * 4);
                v0 = ld_agent_u64(src);
                v1 = ld_agent_u64(src + 1);
            }

            // ---- 4: xproj(t+1) second half hides the read latency ----
            if (t + 1 < SEQ) xproj(t + 1, 2, 4, xpn0, xpn1);

            // ---- 5: stage into LDS, XOR-swizzled at float4 granularity ----
            if (tid < 512) {
                float4 w;
                w.x = u2f((u32)v0); w.y = u2f((u32)(v0 >> 32));
                w.z = u2f((u32)v1); w.w = u2f((u32)(v1 >> 32));
                const int qs = cc ^ ((cc >> 3) & 7);
                *(float4*)(&lh[bt * 512 + qs * 4]) = w;
            }
        } else {
            xproj(1, 0, 4, xpn0, xpn1);
        }
        __syncthreads();                    // (S) staged

        // ---- 6: h-dot on fused x partials, butterfly, gpre write ----
        #pragma unroll
        for (int b = 0; b < 4; ++b) {
            float a0 = xpc0[b], a1 = xpc1[b];
            if (t > 0) {
                const float* hb = &lh[b * 512];
                float4 o0 = *(const float4*)(hb + ((4 * ks + 0) ^ xr) * 4);
                float4 o1 = *(const float4*)(hb + ((4 * ks + 1) ^ xr) * 4);
                float4 o2 = *(const float4*)(hb + ((4 * ks + 2) ^ xr) * 4);
                float4 o3 = *(const float4*)(hb + ((4 * ks + 3) ^ xr) * 4);
                a0 = fmaf(wh0[0].x,o0.x,a0); a0 = fmaf(wh0[0].y,o0.y,a0); a0 = fmaf(wh0[0].z,o0.z,a0); a0 = fmaf(wh0[0].w,o0.w,a0);
                a0 = fmaf(wh0[1].x,o1.x,a0); a0 = fmaf(wh0[1].y,o1.y,a0); a0 = fmaf(wh0[1].z,o1.z,a0); a0 = fmaf(wh0[1].w,o1.w,a0);
                a0 = fmaf(wh0[2].x,o2.x,a0); a0 = fmaf(wh0[2].y,o2.y,a0); a0 = fmaf(wh0[2].z,o2.z,a0); a0 = fmaf(wh0[2].w,o2.w,a0);
                a0 = fmaf(wh0[3].x,o3.x,a0); a0 = fmaf(wh0[3].y,o3.y,a0); a0 = fmaf(wh0[3].z,o3.z,a0); a0 = fmaf(wh0[3].w,o3.w,a0);
                a1 = fmaf(wh1[0].x,o0.x,a1); a1 = fmaf(wh1[0].y,o0.y,a1); a1 = fmaf(wh1[0].z,o0.z,a1); a1 = fmaf(wh1[0].w,o0.w,a1);
                a1 = fmaf(wh1[1].x,o1.x,a1); a1 = fmaf(wh1[1].y,o1.y,a1); a1 = fmaf(wh1[1].z,o1.z,a1); a1 = fmaf(wh1[1].w,o1.w,a1);
                a1 = fmaf(wh1[2].x,o2.x,a1); a1 = fmaf(wh1[2].y,o2.y,a1); a1 = fmaf(wh1[2].z,o2.z,a1); a1 = fmaf(wh1[2].w,o2.w,a1);
                a1 = fmaf(wh1[3].x,o3.x,a1); a1 = fmaf(wh1[3].y,o3.y,a1); a1 = fmaf(wh1[3].z,o3.z,a1); a1 = fmaf(wh1[3].w,o3.w,a1);
            }
            #pragma unroll
            for (int m = 16; m >= 1; m >>= 1) {
                a0 += __shfl_xor(a0, m);
                a1 += __shfl_xor(a1, m);
            }
            if ((tid & 31) == 0) {
                gpre[r0][b]     = a0;
                gpre[r0 + 1][b] = a1;
            }
        }
        __syncthreads();                    // (B) gates ready; lh free

        // ---- 7: tail (wave 0, 64 lanes): gates + agent store + ack + beacon
        if (tid < 64) {
            int b = tid >> 4, dl = tid & 15;
            float iv = gpre[0  + dl][b] + lbias[0  + dl];
            float fv = gpre[16 + dl][b] + lbias[16 + dl];
            float gv = gpre[32 + dl][b] + lbias[32 + dl];
            float ov = gpre[48 + dl][b] + lbias[48 + dl];
            iv = 1.f / (1.f + __expf(-iv));
            fv = 1.f / (1.f + __expf(-fv));
            gv = tanhf(gv);
            ov = 1.f / (1.f + __expf(-ov));
            float c = fv * c_reg + iv * gv;
            float h = ov * tanhf(c);
            c_reg = c; h_keep = h; c_keep = c;
            st_agent_f32(out + (size_t)t * BATCH * HSZ + (size_t)(B4 + b) * HSZ + (d0 + dl), h);
            if (t + 1 < SEQ) {
                asm volatile("s_waitcnt vmcnt(0)" ::: "memory");   // h ack'd
                if (tid == 0) st_agent_u32(ws + grp * NPROD + rank, (u32)(t + 1));
            }
        }

        #pragma unroll
        for (int b = 0; b < 4; ++b) { xpc0[b] = xpn0[b]; xpc1[b] = xpn1[b]; }
    }

    // epilogue: h_last, c_last (tail lanes hold the state)
    if (tid < 64) {
        int b = tid >> 4, dl = tid & 15;
        size_t base = (size_t)SEQ * BATCH * HSZ;
        out[base + (size_t)(B4 + b) * HSZ + (d0 + dl)] = h_keep;                        // h_last
        out[base + (size_t)BATCH * HSZ + (size_t)(B4 + b) * HSZ + (d0 + dl)] = c_keep;  // c_last
    }
}

extern "C" void kernel_launch(void* const* d_in, const int* in_sizes, int n_in,
                              void* d_out, int out_size, void* d_ws, size_t ws_size,
                              hipStream_t stream) {
    const float* inp  = (const float*)d_in[0];
    const float* w_ii = (const float*)d_in[1];
    const float* w_hi = (const float*)d_in[2];
    const float* b_ii = (const float*)d_in[3];
    const float* b_hi = (const float*)d_in[4];
    const float* w_if = (const float*)d_in[5];
    const float* w_hf = (const float*)d_in[6];
    const float* b_if = (const float*)d_in[7];
    const float* b_hf = (const float*)d_in[8];
    const float* w_io = (const float*)d_in[9];
    const float* w_ho = (const float*)d_in[10];
    const float* b_io = (const float*)d_in[11];
    const float* b_ho = (const float*)d_in[12];
    const float* w_ig = (const float*)d_in[13];
    const float* w_hg = (const float*)d_in[14];
    const float* b_ig = (const float*)d_in[15];
    const float* b_hg = (const float*)d_in[16];
    float* out = (float*)d_out;
    u32* ws = (u32*)d_ws;

    hipMemsetAsync(d_ws, 0, 4096, stream);  // zero beacons each launch

    void* args[] = { (void*)&inp,
                     (void*)&w_ii, (void*)&w_hi, (void*)&b_ii, (void*)&b_hi,
                     (void*)&w_if, (void*)&w_hf, (void*)&b_if, (void*)&b_hf,
                     (void*)&w_io, (void*)&w_ho, (void*)&b_io, (void*)&b_ho,
                     (void*)&w_ig, (void*)&w_hg, (void*)&b_ig, (void*)&b_hg,
                     (void*)&out, (void*)&ws };
    hipError_t err = hipLaunchCooperativeKernel((const void*)lstm_persistent,
                                                dim3(GRID), dim3(TPB), args, 0, stream);
    if (err != hipSuccess) {
        lstm_persistent<<<dim3(GRID), dim3(TPB), 0, stream>>>(
            inp, w_ii, w_hi, b_ii, b_hi, w_if, w_hf, b_if, b_hf,
            w_io, w_ho, b_io, b_ho, w_ig, w_hg, b_ig, b_hg, out, ws);
    }
}